// Round 3
// baseline (603.752 us; speedup 1.0000x reference)
//
#include <hip/hip_runtime.h>

#define NB   256   // batch
#define NT   512   // time steps
#define NF   33    // features incl. flag channel
#define NFP  36    // padded x row (floats; 144 B, 16B-aligned)
#define BOND 64
#define NOUT 32

typedef _Float16 h2 __attribute__((ext_vector_type(2)));
typedef float    f4 __attribute__((ext_vector_type(4)));

__device__ __forceinline__ float fdot2(h2 p, h2 q, float c) {
    return __builtin_amdgcn_fdot2(p, q, c, false);   // v_dot2_f32_f16
}

__device__ __forceinline__ h2 pk2(float a, float b) {
    auto r = __builtin_amdgcn_cvt_pkrtz(a, b);       // v_cvt_pkrtz_f16_f32
    return __builtin_bit_cast(h2, r);
}

// One chain step.
//  lane = (jl = 8w + lane&7, ib = lane>>3): partial for output j=jl over i in [8ib, 8ib+8)
//  xq/x0 hold x[t]'s features (preloaded); this routine prefetches x[tnext] before
//  the barrier so the LDS latency drains inside the barrier wait.
__device__ __forceinline__ void step_t(int parity, int tnext,
                                       const h2 (&creg)[32][4], h2 (&vp)[4],
                                       f4 (&xq)[8], float& x0, float& vj,
                                       float (*__restrict__ vbuf)[BOND],
                                       const float* __restrict__ xlds,
                                       int ib, int jl, bool writer)
{
    // 4 independent accumulator chains over f
    float a0 = 0.f, a1 = 0.f, a2 = 0.f, a3 = 0.f;
    #pragma unroll
    for (int fq = 0; fq < 8; ++fq) {
        #pragma unroll
        for (int m = 0; m < 4; ++m) {
            const int ff = 4 * fq + m;
            float t0 = fdot2(vp[0], creg[ff][0], 0.f);
            t0 = fdot2(vp[1], creg[ff][1], t0);
            t0 = fdot2(vp[2], creg[ff][2], t0);
            t0 = fdot2(vp[3], creg[ff][3], t0);
            float xf = xq[fq][m];
            if (m == 0)      a0 = fmaf(xf, t0, a0);
            else if (m == 1) a1 = fmaf(xf, t0, a1);
            else if (m == 2) a2 = fmaf(xf, t0, a2);
            else             a3 = fmaf(xf, t0, a3);
        }
    }
    float acc = (a0 + a1) + (a2 + a3);

    // in-wave butterfly over the 8 i-blocks (lanes l, l^8, l^16, l^32)
    acc += __shfl_xor(acc, 8, 64);
    acc += __shfl_xor(acc, 16, 64);
    acc += __shfl_xor(acc, 32, 64);

    float vnew = fmaf(x0, vj, acc);      // exact fp32 identity (flag) channel
    vj = vnew;
    if (writer) vbuf[parity][jl] = vnew; // lanes with ib==0: 8 f32 per wave

    // prefetch next x row from (static) xlds BEFORE the barrier
    {
        const float* xr = xlds + tnext * NFP;
        #pragma unroll
        for (int k = 0; k < 8; ++k) xq[k] = *(const f4*)(xr + 4 * k);
        x0 = xr[32];
    }

    __syncthreads();

    // reload this lane's v pairs (broadcast, 2-way bank aliasing = free)
    const float* vb = &vbuf[parity][ib << 3];
    f4 va = *(const f4*)vb;
    f4 vc = *(const f4*)(vb + 4);
    vp[0] = pk2(va.x, va.y);
    vp[1] = pk2(va.z, va.w);
    vp[2] = pk2(vc.x, vc.y);
    vp[3] = pk2(vc.z, vc.w);
}

__global__ __launch_bounds__(512, 2)
void umps_chain(const float* __restrict__ x,
                const float* __restrict__ core,
                const float* __restrict__ alpha,
                const float* __restrict__ oc,
                float* __restrict__ out)
{
    const int tid  = (int)threadIdx.x;
    const int lane = tid & 63;
    const int w    = tid >> 6;            // 0..7
    const int ib   = lane >> 3;           // i-block: i in [8ib, 8ib+8)
    const int jl   = (w << 3) + (lane & 7);  // this lane's output j
    const int b    = (int)blockIdx.x;

    // x rows rotated: row[k] = x[t, k+1] for k<32 (quads 16B-aligned), row[32] = x[t,0]
    __shared__ __align__(16) float xlds[(NT + 1) * NFP];  // +1 row: prefetch overrun pad
    __shared__ float vbuf[2][BOND];

    // ---- stage this batch's x into LDS (one-time, rotated layout) ----
    const float* xb = x + (size_t)b * (NT * NF);
    for (int idx = tid; idx < NT * NF; idx += 512) {
        int t = idx / NF;
        int f = idx - t * NF;
        int k = (f == 0) ? 32 : (f - 1);
        xlds[t * NFP + k] = xb[idx];
    }

    // ---- core slice into VGPRs: creg[ff][p] = (C[8ib+2p, ff+1, jl], C[8ib+2p+1, ff+1, jl]) ----
    h2 creg[32][4];
    {
        const float* cb = core + (size_t)(8 * ib) * (NF * BOND) + BOND + jl;
        #pragma unroll
        for (int p = 0; p < 4; ++p) {
            const float* c0 = cb + (size_t)(2 * p) * (NF * BOND);
            const float* c1 = cb + (size_t)(2 * p + 1) * (NF * BOND);
            #pragma unroll
            for (int ff = 0; ff < 32; ++ff)
                creg[ff][p] = pk2(c0[ff * BOND], c1[ff * BOND]);
        }
    }

    // ---- init carry ----
    float vj = alpha[jl];                 // lane's fp32 copy of v[jl]
    h2 vp[4];
    #pragma unroll
    for (int k = 0; k < 4; ++k)
        vp[k] = pk2(alpha[8 * ib + 2 * k], alpha[8 * ib + 2 * k + 1]);

    __syncthreads();   // xlds ready

    // preload x for t=0
    f4 xq[8];
    float x0;
    {
        const float* xr = xlds;
        #pragma unroll
        for (int k = 0; k < 8; ++k) xq[k] = *(const f4*)(xr + 4 * k);
        x0 = xr[32];
    }

    const bool writer = (ib == 0);

    #pragma unroll 1
    for (int t = 0; t < NT; t += 2) {
        step_t(0, t + 1, creg, vp, xq, x0, vj, vbuf, xlds, ib, jl, writer);
        step_t(1, t + 2, creg, vp, xq, x0, vj, vbuf, xlds, ib, jl, writer);
    }
    // final v is in vbuf[1][:], synced by the barrier inside the last step

    // ---- epilogue: out[b,:] = v @ output_core (64 x 32) ----
    if (tid < NOUT) {
        float s = 0.f;
        #pragma unroll
        for (int jj = 0; jj < BOND; ++jj)
            s = fmaf(vbuf[1][jj], oc[jj * NOUT + tid], s);
        out[b * NOUT + tid] = s;
    }
}

extern "C" void kernel_launch(void* const* d_in, const int* in_sizes, int n_in,
                              void* d_out, int out_size, void* d_ws, size_t ws_size,
                              hipStream_t stream) {
    const float* x     = (const float*)d_in[0];  // (256, 512, 33) f32
    const float* core  = (const float*)d_in[1];  // (64, 33, 64) f32
    const float* alpha = (const float*)d_in[2];  // (64,) f32
    const float* oc    = (const float*)d_in[3];  // (64, 32) f32
    float* out = (float*)d_out;                  // (256, 32) f32

    umps_chain<<<dim3(NB), dim3(512), 0, stream>>>(x, core, alpha, oc, out);
}